// Round 1
// 437.033 us; speedup vs baseline: 1.1543x; 1.1543x over previous
//
#include <hip/hip_runtime.h>
#include <hip/hip_bf16.h>

typedef unsigned short u16;
typedef __attribute__((ext_vector_type(8))) short bf16x8;    // 8 bf16 in 4 VGPRs
typedef __attribute__((ext_vector_type(4))) float f32x4;

static __device__ __forceinline__ u16 f2bf(float f) {
    unsigned u = __float_as_uint(f);
    unsigned r = (u + 0x7fffu + ((u >> 16) & 1u)) >> 16;   // RNE
    return (u16)r;
}
static __device__ __forceinline__ float bf2f(u16 u) {
    return __uint_as_float(((unsigned)u) << 16);
}

static __device__ __forceinline__ void async_copy16(const void* gptr, void* lptr) {
    __builtin_amdgcn_global_load_lds(
        (const __attribute__((address_space(1))) void*)gptr,
        (__attribute__((address_space(3))) void*)lptr, 16, 0, 0);
}

// ---------------------------------------------------------------------------
// fp32 -> bf16 for all three inputs in ONE launch.
// ---------------------------------------------------------------------------
__global__ __launch_bounds__(256)
void cvt_all(const float* __restrict__ a, const float* __restrict__ b,
             const float* __restrict__ c,
             u16* __restrict__ oa, u16* __restrict__ ob, u16* __restrict__ oc) {
    int blk = blockIdx.x;
    const float* src; u16* dst; long base;
    if (blk < 16384)      { src = a; dst = oa; base = blk; }
    else if (blk < 28672) { src = b; dst = ob; base = blk - 16384; }
    else                  { src = c; dst = oc; base = blk - 28672; }
    long i = (base * 256 + threadIdx.x) * 4;
    float4 f = *(const float4*)(src + i);
    u16 o[4] = { f2bf(f.x), f2bf(f.y), f2bf(f.z), f2bf(f.w) };
    *(uint2*)(dst + i) = *(const uint2*)o;
}

// ---------------------------------------------------------------------------
// C[m,n] = sum_k A[m,k] * B[n,k]   (row-major, K contiguous — "BT" gemm)
//
// 256x256 tile, BK=64, 512 threads = 8 waves (2M x 4N), wave tile 128x64 as
// 8x4 frags of mfma_f32_16x16x32_bf16. 8-phase schedule (m201 template):
// per phase {ds_read subtile || 1 half-tile global_load_lds -> bar ->
// lgkmcnt(0) -> setprio(1) 16xMFMA setprio(0) -> bar}; vmcnt(6) ONLY at
// phases 4/8 (3 half-tiles in flight, never drained to 0 in the loop).
//
// LDS (128 KiB): [buf:2][A 256x64 | B 256x64] bf16. Rows stored PERMUTED so
// each half is freed by one phase's reads:
//   A phys row p = Mq*128 + wm*64 + r64   (global row g = wm*128 + Mq*64 + r64)
//   B phys row p = Nq*128 + wn*32 + r32   (global col n = wn*64 + Nq*32 + r32)
// k-chunk XOR swizzle: phys 16B slot = logical_chunk ^ (p&7) -> frag reads hit
// all 8 bank-groups uniformly (8 lanes each = structural minimum). Swizzle is
// applied on the GLOBAL source address at staging (global_load_lds demands
// linear lane*16B LDS dests); reads un-swizzle with the same XOR.
//
// Region-safety (stage target freed-by-read, >=1 end-barrier before issue):
//   reads: ph1 A0(M0)+B0(N0) | ph2 B0(N1) | ph3 A0(M1) | ph4 - |
//          ph5 A1(M0)+B1(N0) | ph6 B1(N1) | ph7 A1(M1) | ph8 -
//   stage: ph1 A(T+1)h1->b1 | ph2 A(T+2)h0->b0 | ph3 B(T+2)h0->b0 |
//          ph4 B(T+2)h1->b0 | ph5 A(T+2)h1->b0 | ph6 A(T+3)h0->b1 |
//          ph7 B(T+3)h0->b1 | ph8 B(T+3)h1->b1
//   vmcnt(6)@ph4: all of tile T+1 landed before ph5; @ph8: T+2 before ph1'.
//
// M mult of 256, N mult of 256, K mult of 128, gridDim.x mult of 8.
// ---------------------------------------------------------------------------
template<bool BF16_OUT>
__global__ __launch_bounds__(512, 2)
void gemm_bt8(const u16* __restrict__ A, const u16* __restrict__ B,
              void* __restrict__ Cout, int M, int N, int K) {
    __shared__ __align__(16) u16 lds[65536];   // 128 KiB

    const int t    = threadIdx.x;              // 0..511
    const int lane = t & 63;
    const int wm   = (t >> 6) >> 2;            // 0..1
    const int wn   = (t >> 6) & 3;             // 0..3
    const int l15  = lane & 15;
    const int hi   = lane >> 4;                // 0..3
    const int l7   = lane & 7;

    // XCD-aware panel remap (bijective since gridDim.x % 8 == 0)
    const int id   = blockIdx.y * gridDim.x + blockIdx.x;
    const int cpx  = gridDim.x >> 3;
    const int bx   = (id & 7) * cpx + ((id >> 3) % cpx);
    const int by   = (id >> 3) / cpx;
    const long rowA = (long)by * 256;
    const long rowB = (long)bx * 256;

    // ---- staging source pointers (pre-swizzled global source) ----
    // thread t covers chunk c = j*512+t of a 128-row half: pl = c>>3, slot=c&7
    const int pl0 = t >> 3;                               // j=0 local row
    const int slotcol = ((t & 7) ^ (pl0 & 7)) * 8;        // same for j=0/1
    const u16* Asrc[2][2]; const u16* Bsrc[2][2];
#pragma unroll
    for (int h = 0; h < 2; h++) {
        int gA0 = h * 64 + pl0;                           // wm-group 0
        int gA1 = 128 + h * 64 + pl0;                     // wm-group 1
        Asrc[h][0] = A + (rowA + gA0) * K + slotcol;
        Asrc[h][1] = A + (rowA + gA1) * K + slotcol;
        int nB0 = (pl0 >> 5) * 64 + h * 32 + (pl0 & 31);
        int nB1 = ((64 + pl0) >> 5) * 64 + h * 32 + (pl0 & 31);
        Bsrc[h][0] = B + (rowB + nB0) * K + slotcol;
        Bsrc[h][1] = B + (rowB + nB1) * K + slotcol;
    }
    const int t8 = t * 8;

    auto STAGE = [&](int bufo, bool isB, int h, int kk) {
        const u16* s0 = (isB ? Bsrc : Asrc)[h][0] + kk;
        const u16* s1 = (isB ? Bsrc : Asrc)[h][1] + kk;
        u16* d = lds + bufo + (isB ? 16384 : 0) + h * 8192 + t8;
        async_copy16(s0, d);
        async_copy16(s1, d + 4096);
    };

    // ---- fragment read offsets (u16 units): addr = region + p*64 + slot*8 ----
    const int aBase = wm * 4096 + l15 * 64;
    const int bBase = 16384 + wn * 2048 + l15 * 64;
    const int sOff0 = (hi ^ l7) * 8;            // ks=0: phys slot (0*4+hi)^l7
    const int sOff1 = ((4 + hi) ^ l7) * 8;      // ks=1

    bf16x8 af[4][2], bg0[2][2], bg1[2][2];
    f32x4 acc[8][4] = {};

    auto LOAD_AF = [&](int bufo, int Mq) {
#pragma unroll
        for (int m = 0; m < 4; m++) {
            const u16* p = lds + bufo + Mq * 8192 + aBase + m * 1024;
            af[m][0] = *(const bf16x8*)(p + sOff0);
            af[m][1] = *(const bf16x8*)(p + sOff1);
        }
    };
    auto LOAD_BG = [&](int bufo, int Nq, bf16x8 (*bg)[2]) {
#pragma unroll
        for (int n = 0; n < 2; n++) {
            const u16* p = lds + bufo + Nq * 8192 + bBase + n * 1024;
            bg[n][0] = *(const bf16x8*)(p + sOff0);
            bg[n][1] = *(const bf16x8*)(p + sOff1);
        }
    };
    auto MFMA_Q = [&](int Mq, int Nq, bf16x8 (*bg)[2]) {
        __builtin_amdgcn_s_setprio(1);
#pragma unroll
        for (int ks = 0; ks < 2; ks++)
#pragma unroll
            for (int m = 0; m < 4; m++)
#pragma unroll
                for (int n = 0; n < 2; n++)
                    acc[Mq * 4 + m][Nq * 2 + n] =
                        __builtin_amdgcn_mfma_f32_16x16x32_bf16(
                            af[m][ks], bg[n][ks], acc[Mq * 4 + m][Nq * 2 + n],
                            0, 0, 0);
        __builtin_amdgcn_s_setprio(0);
    };

#define BAR()   __builtin_amdgcn_s_barrier()
#define WAITL() do { asm volatile("s_waitcnt lgkmcnt(0)" ::: "memory"); \
                     __builtin_amdgcn_sched_barrier(0); } while (0)
#define VM6()   asm volatile("s_waitcnt vmcnt(6)" ::: "memory")

    // ---- prologue: tile0 -> buf0 (4 halves), tile1 -> buf1 (3 halves) ----
    STAGE(0, false, 0, 0);  STAGE(0, false, 1, 0);
    STAGE(0, true,  0, 0);  STAGE(0, true,  1, 0);
    STAGE(32768, false, 0, 64);
    STAGE(32768, true,  0, 64);  STAGE(32768, true, 1, 64);
    VM6();                                  // oldest 8 (= all of tile0) landed
    BAR();

#pragma unroll 1
    for (int k0 = 0; k0 < K; k0 += 128) {
        int kN1 = k0 + 64;                              // tile T+1 (< K always)
        int kN2 = k0 + 128; if (kN2 >= K) kN2 = 0;      // tile T+2 (wrap: junk,
        int kN3 = k0 + 192; if (kN3 >= K) kN3 -= K;     //  never read)
        // ph1: read buf0 A(M0)+B(N0); stage A(T+1)h1 -> buf1
        LOAD_AF(0, 0); LOAD_BG(0, 0, bg0);
        STAGE(32768, false, 1, kN1);
        BAR(); WAITL();
        MFMA_Q(0, 0, bg0); BAR();
        // ph2: read buf0 B(N1); stage A(T+2)h0 -> buf0 (freed ph1)
        LOAD_BG(0, 1, bg1);
        STAGE(0, false, 0, kN2);
        BAR(); WAITL();
        MFMA_Q(0, 1, bg1); BAR();
        // ph3: read buf0 A(M1); stage B(T+2)h0 -> buf0 (freed ph1)
        LOAD_AF(0, 1);
        STAGE(0, true, 0, kN2);
        BAR(); WAITL();
        MFMA_Q(1, 0, bg0); BAR();
        // ph4: stage B(T+2)h1 -> buf0 (freed ph2); vmcnt(6): tile T+1 landed
        STAGE(0, true, 1, kN2);
        VM6();
        BAR();
        MFMA_Q(1, 1, bg1); BAR();
        // ph5: read buf1 A(M0)+B(N0); stage A(T+2)h1 -> buf0 (freed ph3)
        LOAD_AF(32768, 0); LOAD_BG(32768, 0, bg0);
        STAGE(0, false, 1, kN2);
        BAR(); WAITL();
        MFMA_Q(0, 0, bg0); BAR();
        // ph6: read buf1 B(N1); stage A(T+3)h0 -> buf1 (freed ph5)
        LOAD_BG(32768, 1, bg1);
        STAGE(32768, false, 0, kN3);
        BAR(); WAITL();
        MFMA_Q(0, 1, bg1); BAR();
        // ph7: read buf1 A(M1); stage B(T+3)h0 -> buf1 (freed ph5)
        LOAD_AF(32768, 1);
        STAGE(32768, true, 0, kN3);
        BAR(); WAITL();
        MFMA_Q(1, 0, bg0); BAR();
        // ph8: stage B(T+3)h1 -> buf1 (freed ph6); vmcnt(6): tile T+2 landed
        STAGE(32768, true, 1, kN3);
        VM6();
        BAR();
        MFMA_Q(1, 1, bg1); BAR();
    }
    // drain in-flight LDS-targeted loads before LDS dealloc at endpgm
    asm volatile("s_waitcnt vmcnt(0)" ::: "memory");

#undef BAR
#undef WAITL
#undef VM6

    // ---- epilogue: 16x16 C/D layout col=lane&15, row=(lane>>4)*4+r ----
    const long crowBase = rowA + wm * 128 + hi * 4;
    const long ccolBase = rowB + wn * 64 + l15;
#pragma unroll
    for (int mi = 0; mi < 8; mi++) {
#pragma unroll
        for (int nj = 0; nj < 4; nj++) {
            long base = (crowBase + mi * 16) * N + ccolBase + nj * 16;
#pragma unroll
            for (int r = 0; r < 4; r++) {
                float v = acc[mi][nj][r];
                long idx = base + (long)r * N;
                if (BF16_OUT) ((u16*)Cout)[idx] = f2bf(v);
                else          ((float*)Cout)[idx] = v;
            }
        }
    }
}

// ---------------------------------------------------------------------------
// Fused Bx-product + depthwise causal conv(L=3) + C-gate.
// BCx: (8192, 6144) bf16 rows = [B(0:2048) | C(2048:4096) | x(4096:6144)]
// y[s,h] = C[s,h] * ( w[h,0]*Bx[s-2,h] + w[h,1]*Bx[s-1,h] + w[h,2]*Bx[s,h] )
// batch boundary: s resets every 4096 rows (zero left-pad per batch)
// ---------------------------------------------------------------------------
union U16x8 { uint4 v; u16 u[8]; };

__global__ __launch_bounds__(256)
void conv_fuse(const u16* __restrict__ BCx, const float* __restrict__ cw,
               u16* __restrict__ y) {
    const int row = blockIdx.x;            // 0..8191
    const int h0  = threadIdx.x * 8;       // 256*8 = 2048
    const int sl  = row & 4095;
    const u16* r0 = BCx + (long)row * 6144;

    U16x8 B0, X0, C0, B1, X1, B2, X2;
    B0.v = *(const uint4*)(r0 + h0);
    C0.v = *(const uint4*)(r0 + 2048 + h0);
    X0.v = *(const uint4*)(r0 + 4096 + h0);
    if (sl >= 1) {
        B1.v = *(const uint4*)(r0 - 6144 + h0);
        X1.v = *(const uint4*)(r0 - 6144 + 4096 + h0);
    } else { B1.v = make_uint4(0,0,0,0); X1.v = make_uint4(0,0,0,0); }
    if (sl >= 2) {
        B2.v = *(const uint4*)(r0 - 12288 + h0);
        X2.v = *(const uint4*)(r0 - 12288 + 4096 + h0);
    } else { B2.v = make_uint4(0,0,0,0); X2.v = make_uint4(0,0,0,0); }

    U16x8 o;
#pragma unroll
    for (int i = 0; i < 8; i++) {
        int h = h0 + i;
        float bx0 = bf2f(B0.u[i]) * bf2f(X0.u[i]);   // tap l=2 (current)
        float bx1 = bf2f(B1.u[i]) * bf2f(X1.u[i]);   // tap l=1 (s-1)
        float bx2 = bf2f(B2.u[i]) * bf2f(X2.u[i]);   // tap l=0 (s-2)
        float v = cw[h*3+2] * bx0 + cw[h*3+1] * bx1 + cw[h*3] * bx2;
        o.u[i] = f2bf(v * bf2f(C0.u[i]));
    }
    *(uint4*)(y + (long)row * 2048 + h0) = o.v;
}

// ---------------------------------------------------------------------------
extern "C" void kernel_launch(void* const* d_in, const int* in_sizes, int n_in,
                              void* d_out, int out_size, void* d_ws, size_t ws_size,
                              hipStream_t stream) {
    const float* hs   = (const float*)d_in[0];   // (2,4096,2048)
    const float* Win  = (const float*)d_in[1];   // (6144,2048)
    const float* cw   = (const float*)d_in[2];   // (2048,1,3)
    const float* Wout = (const float*)d_in[3];   // (2048,2048)
    float* out = (float*)d_out;                  // (2,4096,2048) fp32

    char* ws = (char*)d_ws;
    u16* hsb   = (u16*)(ws);                     //  33,554,432 B
    u16* Winb  = (u16*)(ws +  33554432);         //  25,165,824 B
    u16* Woutb = (u16*)(ws +  58720256);         //   8,388,608 B
    u16* bcx   = (u16*)(ws +  67108864);         // 100,663,296 B
    u16* yb    = (u16*)(ws + 167772160);         //  33,554,432 B  (end 201,326,592)

    cvt_all<<<32768, 256, 0, stream>>>(hs, Win, Wout, hsb, Winb, Woutb);

    // BCx = hs @ Win^T : M=8192, N=6144, K=2048  (grid 24x32 = 768 blocks)
    gemm_bt8<true ><<<dim3(24, 32), 512, 0, stream>>>(hsb, Winb, bcx, 8192, 6144, 2048);

    conv_fuse<<<8192, 256, 0, stream>>>(bcx, cw, yb);

    // out = y @ Wout^T : M=8192, N=2048, K=2048  (grid 8x32 = 256 blocks)
    gemm_bt8<false><<<dim3(8, 32), 512, 0, stream>>>(yb, Woutb, out, 8192, 2048, 2048);
}